// Round 1
// baseline (408.476 us; speedup 1.0000x reference)
//
#include <hip/hip_runtime.h>

#define D        64
#define BINROWS  64
#define SUBCAP   256        // slots per (shard,bin): mean ~161, sigma ~12.7 -> +7.4 sigma
#define NSHARD   8
#define NBINS_MAX 1568      // 224*7 (scan layout); n=100k -> 1563 bins used
#define CHUNK    3072       // was 4096; 49.4 KB LDS -> 3 blocks/CU
#define PER_TH   (CHUNK / 256)   // 12
#define FS16     72         // bf16 facc row stride: 144 B rows, 16B-aligned, 2-way banks (free)
#define CURSTRIDE 16        // ints per cursor -> own 64 B line

typedef __attribute__((ext_vector_type(8))) short short8;
typedef __attribute__((ext_vector_type(4))) float floatx4;

__device__ __forceinline__ unsigned short f2bf(float f) {
    unsigned u = __float_as_uint(f);
    u += 0x7fffu + ((u >> 16) & 1u);   // RNE
    return (unsigned short)(u >> 16);
}
__device__ __forceinline__ float bf2f(unsigned short u) {
    return __uint_as_float(((unsigned)u) << 16);
}

// ---------------------------------------------------------------------------
// Expand v5: v4 structure (register payloads + 1568-bin LDS counting sort +
// sorted run-coalesced write-out) with:
//   - convert (ebs fp32->bf16) folded in as a grid-stride prologue
//   - wfrag pack folded into blocks 0..3
//   - offs[] dropped (derived as cur-hist after Phase C) + CHUNK 3072
//     -> 49.4 KB LDS -> 3 blocks/CU (was 2)
// payload.x = (m<<23)|(rowInBin<<17)|col   payload.y = val bits
// ---------------------------------------------------------------------------
__global__ __launch_bounds__(256) void expand_bin_kernel(
    const int* __restrict__ LI_rows, const int* __restrict__ LI_cols, const float* __restrict__ LI_vals,
    const int* __restrict__ L_rows,  const int* __restrict__ L_cols,  const float* __restrict__ L_vals,
    int* __restrict__ cursorP, uint2* __restrict__ seg, int E, int nbins,
    const float* __restrict__ ebs, unsigned short* __restrict__ ebs16, int total4,
    const float* __restrict__ W_side, const float* __restrict__ W_dot,
    unsigned short* __restrict__ Wfrag)
{
    __shared__ uint2 sorted[CHUNK];               // 24 KB
    __shared__ unsigned short sbin[CHUNK];        // 6 KB
    __shared__ int hist[NBINS_MAX];               // 6.125 KB
    __shared__ int cur[NBINS_MAX];
    __shared__ int gbase[NBINS_MAX];
    __shared__ int tsum[256];

    int t  = threadIdx.x;

    // ---- folded-in convert: ebs fp32 -> bf16 (grid-stride) ----
    for (int i = blockIdx.x * 256 + t; i < total4; i += gridDim.x * 256) {
        float4 v = ((const float4*)ebs)[i];
        ushort4 o;
        o.x = f2bf(v.x); o.y = f2bf(v.y); o.z = f2bf(v.z); o.w = f2bf(v.w);
        ((ushort4*)ebs16)[i] = o;
    }
    // ---- folded-in wfrag pack (blocks 0..3 = 1024 threads = 16 frags) ----
    if (blockIdx.x < 4) {
        int tt = blockIdx.x * 256 + t;
        int f = tt >> 6;
        int l = tt & 63;
        int jt = f >> 2, kt = f & 3;
        int q = l >> 4, nl = l & 15;
        int nn = jt * 16 + nl;
#pragma unroll
        for (int j = 0; j < 8; ++j) {
            int k = kt * 32 + q * 8 + j;
            float w = (k < 64) ? W_side[k * 64 + nn] : W_dot[(k - 64) * 64 + nn];
            Wfrag[(size_t)f * 512 + l * 8 + j] = f2bf(w);
        }
    }

    int c0 = blockIdx.x * CHUNK;
    int sh = blockIdx.x & (NSHARD - 1);
    int twoE = 2 * E;
    int chunkcnt = twoE - c0; if (chunkcnt > CHUNK) chunkcnt = CHUNK;

    for (int b = t; b < NBINS_MAX; b += 256) hist[b] = 0;
    __syncthreads();

    unsigned rm[PER_TH];
    uint2    cv[PER_TH];

    // Phase A: read edges into registers, histogram bins
#pragma unroll
    for (int k = 0; k < PER_TH; ++k) {
        int e = c0 + k * 256 + t;
        rm[k] = 0xFFFFFFFFu;
        if (e < twoE) {
            int m = (e >= E) ? 1 : 0;
            int r, cl; float v;
            if (m) { r = L_rows[e - E]; cl = L_cols[e - E]; v = L_vals[e - E]; }
            else   { r = LI_rows[e];    cl = LI_cols[e];    v = LI_vals[e]; }
            rm[k] = (unsigned)r | ((unsigned)m << 17);
            cv[k] = make_uint2((unsigned)cl, __float_as_uint(v));
            atomicAdd(&hist[r >> 6], 1);
        }
    }
    __syncthreads();

    // Phase B: exclusive scan of hist (224 threads x 7 keys + block scan)
    int loc[7]; int tot = 0;
    if (t < 224) {
#pragma unroll
        for (int i = 0; i < 7; ++i) { loc[i] = tot; tot += hist[t * 7 + i]; }
    }
    tsum[t] = (t < 224) ? tot : 0;
    __syncthreads();
    for (int step = 1; step < 256; step <<= 1) {
        int add = (t >= step) ? tsum[t - step] : 0;
        __syncthreads();
        tsum[t] += add;
        __syncthreads();
    }
    int tbase = tsum[t] - ((t < 224) ? tot : 0);
    if (t < 224) {
#pragma unroll
        for (int i = 0; i < 7; ++i) {
            int key = t * 7 + i;
            cur[key] = tbase + loc[i];
        }
    }
    __syncthreads();

    // Phase B2: reserve global runs in this WG's shard (padded cursors)
    for (int b = t; b < nbins; b += 256) {
        int c = hist[b];
        gbase[b] = c ? atomicAdd(&cursorP[(sh * NBINS_MAX + b) * CURSTRIDE], c) : 0;
    }

    // Phase C: scatter payloads into the LDS-sorted array
#pragma unroll
    for (int k = 0; k < PER_TH; ++k) {
        unsigned g = rm[k];
        if (g == 0xFFFFFFFFu) continue;
        int r   = (int)(g & 0x1FFFFu);
        int m   = (int)((g >> 17) & 1u);
        int bin = r >> 6;
        int rank = atomicAdd(&cur[bin], 1);
        sorted[rank] = make_uint2(((unsigned)m << 23) | ((unsigned)(r & 63) << 17) | cv[k].x, cv[k].y);
        sbin[rank]   = (unsigned short)bin;
    }
    __syncthreads();

    // Phase D: coalesced run write-out; offs derived as cur-hist
    for (int i = t; i < chunkcnt; i += 256) {
        int bin = sbin[i];
        int off = cur[bin] - hist[bin];
        int pos = gbase[bin] + (i - off);
        if (pos < SUBCAP)
            seg[((size_t)(sh * NBINS_MAX) + bin) * SUBCAP + pos] = sorted[i];
    }
}

// ---------------------------------------------------------------------------
// Fused v7: v6 branchless-gather structure, but facc stored in BF16
// (stride FS16=72 -> 144 B rows, 16B aligned). LDS drops 36352 -> 19968 B
// -> 8 blocks/CU (was 4), doubling latency hiding for the random gather.
// Epilogue LI fragment is now a single ds_read_b128 (no f2bf chain).
// ---------------------------------------------------------------------------
__global__ __launch_bounds__(256, 8) void fused_kernel(
    const uint2* __restrict__ seg, const int* __restrict__ cursorP,
    const unsigned short* __restrict__ ebs16,
    const float* __restrict__ entity,
    const unsigned short* __restrict__ Wfrag,
    float* __restrict__ out, int n)
{
    __shared__ __align__(16) char shmem[2 * BINROWS * FS16 * 2];  // 18432 B
    __shared__ int hist[128];
    __shared__ int offs[128];
    __shared__ int cur[128];
    uint2* sseg = (uint2*)shmem;                 // sorted entries (<=2048*8 B = 16 KB)
    unsigned short* facc = (unsigned short*)shmem;  // bf16 acc, reused after barrier

    int t = threadIdx.x;
    int b = blockIdx.x;

    if (t < 128) hist[t] = 0;
    __syncthreads();

    // Load per-shard counts + this thread's entries (<=1/shard, SUBCAP==256)
    int clen[NSHARD];
    uint2 held[NSHARD];
    unsigned hmask = 0;
#pragma unroll
    for (int sh = 0; sh < NSHARD; ++sh) {
        int c = cursorP[(sh * NBINS_MAX + b) * CURSTRIDE];
        clen[sh] = c < SUBCAP ? c : SUBCAP;
        if (t < clen[sh]) {
            held[sh] = seg[((size_t)(sh * NBINS_MAX) + b) * SUBCAP + t];
            hmask |= (1u << sh);
            atomicAdd(&hist[(held[sh].x >> 17) & 127u], 1);
        }
    }
    __syncthreads();

    // exclusive scan over 128 keys
    if (t < 128) offs[t] = hist[t];
    __syncthreads();
    for (int step = 1; step < 128; step <<= 1) {
        int add = 0;
        if (t < 128 && t >= step) add = offs[t - step];
        __syncthreads();
        if (t < 128) offs[t] += add;
        __syncthreads();
    }
    if (t < 128) {
        int excl = offs[t] - hist[t];
        offs[t] = excl;
        cur[t]  = excl;
    }
    __syncthreads();

#pragma unroll
    for (int sh = 0; sh < NSHARD; ++sh) {
        if (hmask & (1u << sh)) {
            unsigned key = (held[sh].x >> 17) & 127u;
            int rank = atomicAdd(&cur[key], 1);
            sseg[rank] = held[sh];
        }
    }
    __syncthreads();

    // Accumulate: group g (16 lanes) owns keys [g*8, g*8+8); branchless.
    int g  = t >> 4;
    int l4 = (t & 15) << 2;
    int beg[8], len[8], lenm1[8];
    int maxlen = 0;
#pragma unroll
    for (int kk = 0; kk < 8; ++kk) {
        int key = g * 8 + kk;
        beg[kk]   = offs[key];
        len[kk]   = hist[key];
        lenm1[kk] = len[kk] > 0 ? len[kk] - 1 : 0;
        maxlen = max(maxlen, len[kk]);
    }
    floatx4 a8[8];
#pragma unroll
    for (int kk = 0; kk < 8; ++kk) a8[kk] = (floatx4){0.f, 0.f, 0.f, 0.f};

    for (int s = 0; s < maxlen; ++s) {
#pragma unroll
        for (int kk = 0; kk < 8; ++kk) {
            bool sel = s < len[kk];
            int idx  = beg[kk] + min(s, lenm1[kk]);
            uint2 en = sseg[idx];                       // LDS broadcast
            float vv = sel ? __uint_as_float(en.y) : 0.f;
            // clamped idx always yields a valid in-range entry -> safe addr;
            // vv=0 kills the contribution, so no mask needed on en.x.
            ushort4 x = *(const ushort4*)(ebs16 + (size_t)(en.x & 0x1FFFFu) * D + l4);
            a8[kk][0] += vv * bf2f(x.x);
            a8[kk][1] += vv * bf2f(x.y);
            a8[kk][2] += vv * bf2f(x.z);
            a8[kk][3] += vv * bf2f(x.w);
        }
    }
    __syncthreads();   // all sseg reads done before facc overwrites the union

#pragma unroll
    for (int kk = 0; kk < 8; ++kk) {
        int key = g * 8 + kk;
        ushort4 o;
        o.x = f2bf(a8[kk][0]); o.y = f2bf(a8[kk][1]);
        o.z = f2bf(a8[kk][2]); o.w = f2bf(a8[kk][3]);
        *(ushort4*)(facc + ((size_t)(key >> 6) * BINROWS + (key & 63)) * FS16 + l4) = o;
    }
    __syncthreads();

    // --- MFMA epilogue: wave w owns bin-rows [w*16,+16) ---
    int w = t >> 6;
    int l = t & 63;
    int q = l >> 4, mcol = l & 15;
    int rowbase = b * BINROWS + w * 16;
    int growA = rowbase + mcol;
    int binrow = w * 16 + mcol;
    const unsigned short* faccLI = facc;
    const unsigned short* faccL  = facc + BINROWS * FS16;

    floatx4 accv[4];
#pragma unroll
    for (int jt = 0; jt < 4; ++jt) accv[jt] = (floatx4){0.f, 0.f, 0.f, 0.f};

#pragma unroll
    for (int kt = 0; kt < 4; ++kt) {
        short8 af;
        if (kt < 2) {
            // bf16 fragment is already in the stored format: one ds_read_b128
            af = *(const short8*)(faccLI + (size_t)binrow * FS16 + kt * 32 + q * 8);
        } else {
            short8 lv = *(const short8*)(faccL + (size_t)binrow * FS16 + (kt - 2) * 32 + q * 8);
            float4 e0 = make_float4(0.f, 0.f, 0.f, 0.f), e1 = e0;
            if (growA < n) {
                const float4* ep = (const float4*)(entity + (size_t)growA * D + (kt - 2) * 32 + q * 8);
                e0 = ep[0]; e1 = ep[1];
            }
            af[0] = (short)f2bf(bf2f((unsigned short)lv[0]) * e0.x);
            af[1] = (short)f2bf(bf2f((unsigned short)lv[1]) * e0.y);
            af[2] = (short)f2bf(bf2f((unsigned short)lv[2]) * e0.z);
            af[3] = (short)f2bf(bf2f((unsigned short)lv[3]) * e0.w);
            af[4] = (short)f2bf(bf2f((unsigned short)lv[4]) * e1.x);
            af[5] = (short)f2bf(bf2f((unsigned short)lv[5]) * e1.y);
            af[6] = (short)f2bf(bf2f((unsigned short)lv[6]) * e1.z);
            af[7] = (short)f2bf(bf2f((unsigned short)lv[7]) * e1.w);
        }
#pragma unroll
        for (int jt = 0; jt < 4; ++jt) {
            const short8 bf = *(const short8*)(Wfrag + (size_t)(jt * 4 + kt) * 512 + (size_t)l * 8);
            accv[jt] = __builtin_amdgcn_mfma_f32_16x16x32_bf16(af, bf, accv[jt], 0, 0, 0);
        }
    }

#pragma unroll
    for (int jt = 0; jt < 4; ++jt) {
#pragma unroll
        for (int r = 0; r < 4; ++r) {
            int grow = rowbase + q * 4 + r;
            if (grow < n) {
                float v = accv[jt][r];
                v = v > 0.f ? v : 0.2f * v;
                out[(size_t)grow * D + jt * 16 + mcol] = v;
            }
        }
    }
}

// ---------------------------------------------------------------------------
// Fallback path (workspace too small): R1 atomic scatter + fp32 epilogue.
// ---------------------------------------------------------------------------
__global__ void scatter_kernel(
    const float* __restrict__ LI_vals, const int* __restrict__ LI_rows, const int* __restrict__ LI_cols,
    const float* __restrict__ L_vals,  const int* __restrict__ L_rows,  const int* __restrict__ L_cols,
    const float* __restrict__ ebs,
    float* __restrict__ accLI, float* __restrict__ accL, int E)
{
    long long t = (long long)blockIdx.x * blockDim.x + threadIdx.x;
    long long e2 = t >> 4;
    if (e2 >= 2LL * E) return;
    int c = ((int)t & 15) << 2;
    const float* vals; const int* rows; const int* cols; float* acc; int e;
    if (e2 < E) { vals = LI_vals; rows = LI_rows; cols = LI_cols; acc = accLI; e = (int)e2; }
    else        { vals = L_vals;  rows = L_rows;  cols = L_cols;  acc = accL;  e = (int)(e2 - E); }
    float v = vals[e]; int r = rows[e]; int cl = cols[e];
    const float4 x = *(const float4*)(ebs + (size_t)cl * D + c);
    float* o = acc + (size_t)r * D + c;
    unsafeAtomicAdd(o + 0, v * x.x);
    unsafeAtomicAdd(o + 1, v * x.y);
    unsafeAtomicAdd(o + 2, v * x.z);
    unsafeAtomicAdd(o + 3, v * x.w);
}

__global__ __launch_bounds__(256) void epilogue_kernel(
    const float* __restrict__ acc, const float* __restrict__ entity,
    const float* __restrict__ W_side, const float* __restrict__ W_dot,
    float* __restrict__ out, int n)
{
    int lane = threadIdx.x & 63;
    int wave = (blockIdx.x << 2) | (threadIdx.x >> 6);
    int row  = (wave << 6) + lane;
    bool valid = row < n;
    const float* accLI = acc;
    const float* accL  = acc + (size_t)n * D;
    float a[D], b[D];
    if (valid) {
        const float4* ap = (const float4*)(accLI  + (size_t)row * D);
        const float4* lp = (const float4*)(accL   + (size_t)row * D);
        const float4* ep = (const float4*)(entity + (size_t)row * D);
#pragma unroll
        for (int qq = 0; qq < 16; ++qq) {
            float4 av = ap[qq]; float4 lv = lp[qq]; float4 ev = ep[qq];
            a[4*qq+0] = av.x; a[4*qq+1] = av.y; a[4*qq+2] = av.z; a[4*qq+3] = av.w;
            b[4*qq+0] = lv.x * ev.x; b[4*qq+1] = lv.y * ev.y;
            b[4*qq+2] = lv.z * ev.z; b[4*qq+3] = lv.w * ev.w;
        }
    } else {
#pragma unroll
        for (int qq = 0; qq < D; ++qq) { a[qq] = 0.f; b[qq] = 0.f; }
    }
    float4* op = (float4*)(out + (size_t)row * D);
#pragma unroll 1
    for (int jc = 0; jc < 16; ++jc) {
        float a0 = 0.f, a1 = 0.f, a2 = 0.f, a3 = 0.f;
#pragma unroll
        for (int k = 0; k < D; ++k) {
            float4 w1 = *(const float4*)(W_side + (k << 6) + (jc << 2));
            float4 w2 = *(const float4*)(W_dot  + (k << 6) + (jc << 2));
            a0 += a[k] * w1.x + b[k] * w2.x;
            a1 += a[k] * w1.y + b[k] * w2.y;
            a2 += a[k] * w1.z + b[k] * w2.z;
            a3 += a[k] * w1.w + b[k] * w2.w;
        }
        float4 r;
        r.x = a0 > 0.f ? a0 : 0.2f * a0;
        r.y = a1 > 0.f ? a1 : 0.2f * a1;
        r.z = a2 > 0.f ? a2 : 0.2f * a2;
        r.w = a3 > 0.f ? a3 : 0.2f * a3;
        if (valid) op[jc] = r;
    }
}

extern "C" void kernel_launch(void* const* d_in, const int* in_sizes, int n_in,
                              void* d_out, int out_size, void* d_ws, size_t ws_size,
                              hipStream_t stream) {
    const float* ebs     = (const float*)d_in[0];
    const float* entity  = (const float*)d_in[1];
    const float* W_side  = (const float*)d_in[2];
    const float* W_dot   = (const float*)d_in[3];
    const float* LI_vals = (const float*)d_in[4];
    const float* L_vals  = (const float*)d_in[5];
    const int*   LI_rows = (const int*)d_in[6];
    const int*   LI_cols = (const int*)d_in[7];
    const int*   L_rows  = (const int*)d_in[8];
    const int*   L_cols  = (const int*)d_in[9];
    float* out = (float*)d_out;

    int E = in_sizes[4];
    int n = in_sizes[0] / D;
    int nbins = (n + BINROWS - 1) / BINROWS;

    size_t curBytes = (size_t)NSHARD * NBINS_MAX * CURSTRIDE * sizeof(int);   // 0.80 MB
    size_t segBytes = (size_t)NSHARD * NBINS_MAX * SUBCAP * sizeof(uint2);    // 25.7 MB
    size_t ebsBytes = (size_t)n * D * sizeof(unsigned short);                 // 12.8 MB
    size_t wfBytes  = (size_t)16 * 512 * sizeof(unsigned short);              // 16 KB
    size_t need = curBytes + segBytes + ebsBytes + wfBytes;

    if (ws_size >= need && nbins <= NBINS_MAX && n <= 131072) {
        int*            cursorP = (int*)d_ws;
        uint2*          seg     = (uint2*)((char*)d_ws + curBytes);
        unsigned short* ebs16   = (unsigned short*)((char*)d_ws + curBytes + segBytes);
        unsigned short* Wfrag   = (unsigned short*)((char*)d_ws + curBytes + segBytes + ebsBytes);

        hipMemsetAsync(cursorP, 0, curBytes, stream);

        int total4 = n * D / 4;
        int xblocks = (2 * E + CHUNK - 1) / CHUNK;
        expand_bin_kernel<<<xblocks, 256, 0, stream>>>(
            LI_rows, LI_cols, LI_vals, L_rows, L_cols, L_vals,
            cursorP, seg, E, nbins,
            ebs, ebs16, total4, W_side, W_dot, Wfrag);

        fused_kernel<<<nbins, 256, 0, stream>>>(
            seg, cursorP, ebs16, entity, Wfrag, out, n);
    } else {
        size_t accBytes = (size_t)2 * n * D * sizeof(float);
        float* acc   = (float*)d_ws;
        float* accLI = acc;
        float* accL  = accLI + (size_t)n * D;
        hipMemsetAsync(d_ws, 0, accBytes, stream);
        long long totalThreads = 2LL * E * 16;
        int sblocks = (int)((totalThreads + 255) / 256);
        scatter_kernel<<<sblocks, 256, 0, stream>>>(
            LI_vals, LI_rows, LI_cols, L_vals, L_rows, L_cols, ebs, accLI, accL, E);
        int nTiles = (n + 63) / 64;
        epilogue_kernel<<<(nTiles + 3) / 4, 256, 0, stream>>>(
            acc, entity, W_side, W_dot, out, n);
    }
}

// Round 2
// 228.944 us; speedup vs baseline: 1.7842x; 1.7842x over previous
//
#include <hip/hip_runtime.h>

#define D        64
#define BINROWS  64
#define SUBCAP   256        // slots per (shard,bin): mean ~161, sigma ~12.7 -> +7.4 sigma
#define NSHARD   8
#define NBINS_MAX 1568      // 224*7 (scan layout); n=100k -> 1563 bins used
#define CHUNK    3072       // 49.4 KB LDS -> 3 blocks/CU in expand
#define PER_TH   (CHUNK / 256)   // 12
#define FS16     72         // bf16 facc row stride: 144 B rows, 16B-aligned, 2-way banks (free)
#define CURSTRIDE 16        // ints per cursor -> own 64 B line

typedef __attribute__((ext_vector_type(8))) short short8;
typedef __attribute__((ext_vector_type(4))) float floatx4;

__device__ __forceinline__ unsigned short f2bf(float f) {
    unsigned u = __float_as_uint(f);
    u += 0x7fffu + ((u >> 16) & 1u);   // RNE
    return (unsigned short)(u >> 16);
}
__device__ __forceinline__ float bf2f(unsigned short u) {
    return __uint_as_float(((unsigned)u) << 16);
}

// ---------------------------------------------------------------------------
// Expand v5: register payloads + 1568-bin LDS counting sort + sorted
// run-coalesced write-out; convert (fp32->bf16) and wfrag pack folded in.
// payload.x = (m<<23)|(rowInBin<<17)|col   payload.y = val bits
// ---------------------------------------------------------------------------
__global__ __launch_bounds__(256) void expand_bin_kernel(
    const int* __restrict__ LI_rows, const int* __restrict__ LI_cols, const float* __restrict__ LI_vals,
    const int* __restrict__ L_rows,  const int* __restrict__ L_cols,  const float* __restrict__ L_vals,
    int* __restrict__ cursorP, uint2* __restrict__ seg, int E, int nbins,
    const float* __restrict__ ebs, unsigned short* __restrict__ ebs16, int total4,
    const float* __restrict__ W_side, const float* __restrict__ W_dot,
    unsigned short* __restrict__ Wfrag)
{
    __shared__ uint2 sorted[CHUNK];               // 24 KB
    __shared__ unsigned short sbin[CHUNK];        // 6 KB
    __shared__ int hist[NBINS_MAX];               // 6.125 KB
    __shared__ int cur[NBINS_MAX];
    __shared__ int gbase[NBINS_MAX];
    __shared__ int tsum[256];

    int t  = threadIdx.x;

    // ---- folded-in convert: ebs fp32 -> bf16 (grid-stride) ----
    for (int i = blockIdx.x * 256 + t; i < total4; i += gridDim.x * 256) {
        float4 v = ((const float4*)ebs)[i];
        ushort4 o;
        o.x = f2bf(v.x); o.y = f2bf(v.y); o.z = f2bf(v.z); o.w = f2bf(v.w);
        ((ushort4*)ebs16)[i] = o;
    }
    // ---- folded-in wfrag pack (blocks 0..3 = 1024 threads = 16 frags) ----
    if (blockIdx.x < 4) {
        int tt = blockIdx.x * 256 + t;
        int f = tt >> 6;
        int l = tt & 63;
        int jt = f >> 2, kt = f & 3;
        int q = l >> 4, nl = l & 15;
        int nn = jt * 16 + nl;
#pragma unroll
        for (int j = 0; j < 8; ++j) {
            int k = kt * 32 + q * 8 + j;
            float w = (k < 64) ? W_side[k * 64 + nn] : W_dot[(k - 64) * 64 + nn];
            Wfrag[(size_t)f * 512 + l * 8 + j] = f2bf(w);
        }
    }

    int c0 = blockIdx.x * CHUNK;
    int sh = blockIdx.x & (NSHARD - 1);
    int twoE = 2 * E;
    int chunkcnt = twoE - c0; if (chunkcnt > CHUNK) chunkcnt = CHUNK;

    for (int b = t; b < NBINS_MAX; b += 256) hist[b] = 0;
    __syncthreads();

    unsigned rm[PER_TH];
    uint2    cv[PER_TH];

    // Phase A: read edges into registers, histogram bins
#pragma unroll
    for (int k = 0; k < PER_TH; ++k) {
        int e = c0 + k * 256 + t;
        rm[k] = 0xFFFFFFFFu;
        if (e < twoE) {
            int m = (e >= E) ? 1 : 0;
            int r, cl; float v;
            if (m) { r = L_rows[e - E]; cl = L_cols[e - E]; v = L_vals[e - E]; }
            else   { r = LI_rows[e];    cl = LI_cols[e];    v = LI_vals[e]; }
            rm[k] = (unsigned)r | ((unsigned)m << 17);
            cv[k] = make_uint2((unsigned)cl, __float_as_uint(v));
            atomicAdd(&hist[r >> 6], 1);
        }
    }
    __syncthreads();

    // Phase B: exclusive scan of hist (224 threads x 7 keys + block scan)
    int loc[7]; int tot = 0;
    if (t < 224) {
#pragma unroll
        for (int i = 0; i < 7; ++i) { loc[i] = tot; tot += hist[t * 7 + i]; }
    }
    tsum[t] = (t < 224) ? tot : 0;
    __syncthreads();
    for (int step = 1; step < 256; step <<= 1) {
        int add = (t >= step) ? tsum[t - step] : 0;
        __syncthreads();
        tsum[t] += add;
        __syncthreads();
    }
    int tbase = tsum[t] - ((t < 224) ? tot : 0);
    if (t < 224) {
#pragma unroll
        for (int i = 0; i < 7; ++i) {
            int key = t * 7 + i;
            cur[key] = tbase + loc[i];
        }
    }
    __syncthreads();

    // Phase B2: reserve global runs in this WG's shard (padded cursors)
    for (int b = t; b < nbins; b += 256) {
        int c = hist[b];
        gbase[b] = c ? atomicAdd(&cursorP[(sh * NBINS_MAX + b) * CURSTRIDE], c) : 0;
    }

    // Phase C: scatter payloads into the LDS-sorted array
#pragma unroll
    for (int k = 0; k < PER_TH; ++k) {
        unsigned g = rm[k];
        if (g == 0xFFFFFFFFu) continue;
        int r   = (int)(g & 0x1FFFFu);
        int m   = (int)((g >> 17) & 1u);
        int bin = r >> 6;
        int rank = atomicAdd(&cur[bin], 1);
        sorted[rank] = make_uint2(((unsigned)m << 23) | ((unsigned)(r & 63) << 17) | cv[k].x, cv[k].y);
        sbin[rank]   = (unsigned short)bin;
    }
    __syncthreads();

    // Phase D: coalesced run write-out; offs derived as cur-hist
    for (int i = t; i < chunkcnt; i += 256) {
        int bin = sbin[i];
        int off = cur[bin] - hist[bin];
        int pos = gbase[bin] + (i - off);
        if (pos < SUBCAP)
            seg[((size_t)(sh * NBINS_MAX) + bin) * SUBCAP + pos] = sorted[i];
    }
}

// ---------------------------------------------------------------------------
// Fused v8: bf16 facc (LDS 19968 B -> 8 blocks/CU possible) with NATURAL
// register allocation (__launch_bounds__(256) only). R1's (256,8) hint
// capped VGPRs at 32 and spilled everything to scratch (WRITE_SIZE 25->245
// MB) -- reverted. At the natural ~64 VGPR, 8 waves/SIMD is still legal,
// so occupancy stays LDS-limited at 8 blocks/CU.
// ---------------------------------------------------------------------------
__global__ __launch_bounds__(256) void fused_kernel(
    const uint2* __restrict__ seg, const int* __restrict__ cursorP,
    const unsigned short* __restrict__ ebs16,
    const float* __restrict__ entity,
    const unsigned short* __restrict__ Wfrag,
    float* __restrict__ out, int n)
{
    __shared__ __align__(16) char shmem[2 * BINROWS * FS16 * 2];  // 18432 B
    __shared__ int hist[128];
    __shared__ int offs[128];
    __shared__ int cur[128];
    uint2* sseg = (uint2*)shmem;                 // sorted entries (<=2048*8 B = 16 KB)
    unsigned short* facc = (unsigned short*)shmem;  // bf16 acc, reused after barrier

    int t = threadIdx.x;
    int b = blockIdx.x;

    if (t < 128) hist[t] = 0;
    __syncthreads();

    // Load per-shard counts + this thread's entries (<=1/shard, SUBCAP==256)
    int clen[NSHARD];
    uint2 held[NSHARD];
    unsigned hmask = 0;
#pragma unroll
    for (int sh = 0; sh < NSHARD; ++sh) {
        int c = cursorP[(sh * NBINS_MAX + b) * CURSTRIDE];
        clen[sh] = c < SUBCAP ? c : SUBCAP;
        if (t < clen[sh]) {
            held[sh] = seg[((size_t)(sh * NBINS_MAX) + b) * SUBCAP + t];
            hmask |= (1u << sh);
            atomicAdd(&hist[(held[sh].x >> 17) & 127u], 1);
        }
    }
    __syncthreads();

    // exclusive scan over 128 keys
    if (t < 128) offs[t] = hist[t];
    __syncthreads();
    for (int step = 1; step < 128; step <<= 1) {
        int add = 0;
        if (t < 128 && t >= step) add = offs[t - step];
        __syncthreads();
        if (t < 128) offs[t] += add;
        __syncthreads();
    }
    if (t < 128) {
        int excl = offs[t] - hist[t];
        offs[t] = excl;
        cur[t]  = excl;
    }
    __syncthreads();

#pragma unroll
    for (int sh = 0; sh < NSHARD; ++sh) {
        if (hmask & (1u << sh)) {
            unsigned key = (held[sh].x >> 17) & 127u;
            int rank = atomicAdd(&cur[key], 1);
            sseg[rank] = held[sh];
        }
    }
    __syncthreads();

    // Accumulate: group g (16 lanes) owns keys [g*8, g*8+8); branchless.
    int g  = t >> 4;
    int l4 = (t & 15) << 2;
    int beg[8], len[8], lenm1[8];
    int maxlen = 0;
#pragma unroll
    for (int kk = 0; kk < 8; ++kk) {
        int key = g * 8 + kk;
        beg[kk]   = offs[key];
        len[kk]   = hist[key];
        lenm1[kk] = len[kk] > 0 ? len[kk] - 1 : 0;
        maxlen = max(maxlen, len[kk]);
    }
    floatx4 a8[8];
#pragma unroll
    for (int kk = 0; kk < 8; ++kk) a8[kk] = (floatx4){0.f, 0.f, 0.f, 0.f};

    for (int s = 0; s < maxlen; ++s) {
#pragma unroll
        for (int kk = 0; kk < 8; ++kk) {
            bool sel = s < len[kk];
            int idx  = beg[kk] + min(s, lenm1[kk]);
            uint2 en = sseg[idx];                       // LDS broadcast
            float vv = sel ? __uint_as_float(en.y) : 0.f;
            // clamped idx always yields a valid in-range entry -> safe addr;
            // vv=0 kills the contribution, so no mask needed on en.x.
            ushort4 x = *(const ushort4*)(ebs16 + (size_t)(en.x & 0x1FFFFu) * D + l4);
            a8[kk][0] += vv * bf2f(x.x);
            a8[kk][1] += vv * bf2f(x.y);
            a8[kk][2] += vv * bf2f(x.z);
            a8[kk][3] += vv * bf2f(x.w);
        }
    }
    __syncthreads();   // all sseg reads done before facc overwrites the union

#pragma unroll
    for (int kk = 0; kk < 8; ++kk) {
        int key = g * 8 + kk;
        ushort4 o;
        o.x = f2bf(a8[kk][0]); o.y = f2bf(a8[kk][1]);
        o.z = f2bf(a8[kk][2]); o.w = f2bf(a8[kk][3]);
        *(ushort4*)(facc + ((size_t)(key >> 6) * BINROWS + (key & 63)) * FS16 + l4) = o;
    }
    __syncthreads();

    // --- MFMA epilogue: wave w owns bin-rows [w*16,+16) ---
    int w = t >> 6;
    int l = t & 63;
    int q = l >> 4, mcol = l & 15;
    int rowbase = b * BINROWS + w * 16;
    int growA = rowbase + mcol;
    int binrow = w * 16 + mcol;
    const unsigned short* faccLI = facc;
    const unsigned short* faccL  = facc + BINROWS * FS16;

    floatx4 accv[4];
#pragma unroll
    for (int jt = 0; jt < 4; ++jt) accv[jt] = (floatx4){0.f, 0.f, 0.f, 0.f};

#pragma unroll
    for (int kt = 0; kt < 4; ++kt) {
        short8 af;
        if (kt < 2) {
            // bf16 fragment is already in the stored format: one ds_read_b128
            af = *(const short8*)(faccLI + (size_t)binrow * FS16 + kt * 32 + q * 8);
        } else {
            short8 lv = *(const short8*)(faccL + (size_t)binrow * FS16 + (kt - 2) * 32 + q * 8);
            float4 e0 = make_float4(0.f, 0.f, 0.f, 0.f), e1 = e0;
            if (growA < n) {
                const float4* ep = (const float4*)(entity + (size_t)growA * D + (kt - 2) * 32 + q * 8);
                e0 = ep[0]; e1 = ep[1];
            }
            af[0] = (short)f2bf(bf2f((unsigned short)lv[0]) * e0.x);
            af[1] = (short)f2bf(bf2f((unsigned short)lv[1]) * e0.y);
            af[2] = (short)f2bf(bf2f((unsigned short)lv[2]) * e0.z);
            af[3] = (short)f2bf(bf2f((unsigned short)lv[3]) * e0.w);
            af[4] = (short)f2bf(bf2f((unsigned short)lv[4]) * e1.x);
            af[5] = (short)f2bf(bf2f((unsigned short)lv[5]) * e1.y);
            af[6] = (short)f2bf(bf2f((unsigned short)lv[6]) * e1.z);
            af[7] = (short)f2bf(bf2f((unsigned short)lv[7]) * e1.w);
        }
#pragma unroll
        for (int jt = 0; jt < 4; ++jt) {
            const short8 bf = *(const short8*)(Wfrag + (size_t)(jt * 4 + kt) * 512 + (size_t)l * 8);
            accv[jt] = __builtin_amdgcn_mfma_f32_16x16x32_bf16(af, bf, accv[jt], 0, 0, 0);
        }
    }

#pragma unroll
    for (int jt = 0; jt < 4; ++jt) {
#pragma unroll
        for (int r = 0; r < 4; ++r) {
            int grow = rowbase + q * 4 + r;
            if (grow < n) {
                float v = accv[jt][r];
                v = v > 0.f ? v : 0.2f * v;
                out[(size_t)grow * D + jt * 16 + mcol] = v;
            }
        }
    }
}

// ---------------------------------------------------------------------------
// Fallback path (workspace too small): R1 atomic scatter + fp32 epilogue.
// ---------------------------------------------------------------------------
__global__ void scatter_kernel(
    const float* __restrict__ LI_vals, const int* __restrict__ LI_rows, const int* __restrict__ LI_cols,
    const float* __restrict__ L_vals,  const int* __restrict__ L_rows,  const int* __restrict__ L_cols,
    const float* __restrict__ ebs,
    float* __restrict__ accLI, float* __restrict__ accL, int E)
{
    long long t = (long long)blockIdx.x * blockDim.x + threadIdx.x;
    long long e2 = t >> 4;
    if (e2 >= 2LL * E) return;
    int c = ((int)t & 15) << 2;
    const float* vals; const int* rows; const int* cols; float* acc; int e;
    if (e2 < E) { vals = LI_vals; rows = LI_rows; cols = LI_cols; acc = accLI; e = (int)e2; }
    else        { vals = L_vals;  rows = L_rows;  cols = L_cols;  acc = accL;  e = (int)(e2 - E); }
    float v = vals[e]; int r = rows[e]; int cl = cols[e];
    const float4 x = *(const float4*)(ebs + (size_t)cl * D + c);
    float* o = acc + (size_t)r * D + c;
    unsafeAtomicAdd(o + 0, v * x.x);
    unsafeAtomicAdd(o + 1, v * x.y);
    unsafeAtomicAdd(o + 2, v * x.z);
    unsafeAtomicAdd(o + 3, v * x.w);
}

__global__ __launch_bounds__(256) void epilogue_kernel(
    const float* __restrict__ acc, const float* __restrict__ entity,
    const float* __restrict__ W_side, const float* __restrict__ W_dot,
    float* __restrict__ out, int n)
{
    int lane = threadIdx.x & 63;
    int wave = (blockIdx.x << 2) | (threadIdx.x >> 6);
    int row  = (wave << 6) + lane;
    bool valid = row < n;
    const float* accLI = acc;
    const float* accL  = acc + (size_t)n * D;
    float a[D], b[D];
    if (valid) {
        const float4* ap = (const float4*)(accLI  + (size_t)row * D);
        const float4* lp = (const float4*)(accL   + (size_t)row * D);
        const float4* ep = (const float4*)(entity + (size_t)row * D);
#pragma unroll
        for (int qq = 0; qq < 16; ++qq) {
            float4 av = ap[qq]; float4 lv = lp[qq]; float4 ev = ep[qq];
            a[4*qq+0] = av.x; a[4*qq+1] = av.y; a[4*qq+2] = av.z; a[4*qq+3] = av.w;
            b[4*qq+0] = lv.x * ev.x; b[4*qq+1] = lv.y * ev.y;
            b[4*qq+2] = lv.z * ev.z; b[4*qq+3] = lv.w * ev.w;
        }
    } else {
#pragma unroll
        for (int qq = 0; qq < D; ++qq) { a[qq] = 0.f; b[qq] = 0.f; }
    }
    float4* op = (float4*)(out + (size_t)row * D);
#pragma unroll 1
    for (int jc = 0; jc < 16; ++jc) {
        float a0 = 0.f, a1 = 0.f, a2 = 0.f, a3 = 0.f;
#pragma unroll
        for (int k = 0; k < D; ++k) {
            float4 w1 = *(const float4*)(W_side + (k << 6) + (jc << 2));
            float4 w2 = *(const float4*)(W_dot  + (k << 6) + (jc << 2));
            a0 += a[k] * w1.x + b[k] * w2.x;
            a1 += a[k] * w1.y + b[k] * w2.y;
            a2 += a[k] * w1.z + b[k] * w2.z;
            a3 += a[k] * w1.w + b[k] * w2.w;
        }
        float4 r;
        r.x = a0 > 0.f ? a0 : 0.2f * a0;
        r.y = a1 > 0.f ? a1 : 0.2f * a1;
        r.z = a2 > 0.f ? a2 : 0.2f * a2;
        r.w = a3 > 0.f ? a3 : 0.2f * a3;
        if (valid) op[jc] = r;
    }
}

extern "C" void kernel_launch(void* const* d_in, const int* in_sizes, int n_in,
                              void* d_out, int out_size, void* d_ws, size_t ws_size,
                              hipStream_t stream) {
    const float* ebs     = (const float*)d_in[0];
    const float* entity  = (const float*)d_in[1];
    const float* W_side  = (const float*)d_in[2];
    const float* W_dot   = (const float*)d_in[3];
    const float* LI_vals = (const float*)d_in[4];
    const float* L_vals  = (const float*)d_in[5];
    const int*   LI_rows = (const int*)d_in[6];
    const int*   LI_cols = (const int*)d_in[7];
    const int*   L_rows  = (const int*)d_in[8];
    const int*   L_cols  = (const int*)d_in[9];
    float* out = (float*)d_out;

    int E = in_sizes[4];
    int n = in_sizes[0] / D;
    int nbins = (n + BINROWS - 1) / BINROWS;

    size_t curBytes = (size_t)NSHARD * NBINS_MAX * CURSTRIDE * sizeof(int);   // 0.80 MB
    size_t segBytes = (size_t)NSHARD * NBINS_MAX * SUBCAP * sizeof(uint2);    // 25.7 MB
    size_t ebsBytes = (size_t)n * D * sizeof(unsigned short);                 // 12.8 MB
    size_t wfBytes  = (size_t)16 * 512 * sizeof(unsigned short);              // 16 KB
    size_t need = curBytes + segBytes + ebsBytes + wfBytes;

    if (ws_size >= need && nbins <= NBINS_MAX && n <= 131072) {
        int*            cursorP = (int*)d_ws;
        uint2*          seg     = (uint2*)((char*)d_ws + curBytes);
        unsigned short* ebs16   = (unsigned short*)((char*)d_ws + curBytes + segBytes);
        unsigned short* Wfrag   = (unsigned short*)((char*)d_ws + curBytes + segBytes + ebsBytes);

        hipMemsetAsync(cursorP, 0, curBytes, stream);

        int total4 = n * D / 4;
        int xblocks = (2 * E + CHUNK - 1) / CHUNK;
        expand_bin_kernel<<<xblocks, 256, 0, stream>>>(
            LI_rows, LI_cols, LI_vals, L_rows, L_cols, L_vals,
            cursorP, seg, E, nbins,
            ebs, ebs16, total4, W_side, W_dot, Wfrag);

        fused_kernel<<<nbins, 256, 0, stream>>>(
            seg, cursorP, ebs16, entity, Wfrag, out, n);
    } else {
        size_t accBytes = (size_t)2 * n * D * sizeof(float);
        float* acc   = (float*)d_ws;
        float* accLI = acc;
        float* accL  = accLI + (size_t)n * D;
        hipMemsetAsync(d_ws, 0, accBytes, stream);
        long long totalThreads = 2LL * E * 16;
        int sblocks = (int)((totalThreads + 255) / 256);
        scatter_kernel<<<sblocks, 256, 0, stream>>>(
            LI_vals, LI_rows, LI_cols, L_vals, L_rows, L_cols, ebs, accLI, accL, E);
        int nTiles = (n + 63) / 64;
        epilogue_kernel<<<(nTiles + 3) / 4, 256, 0, stream>>>(
            acc, entity, W_side, W_dot, out, n);
    }
}